// Round 1
// baseline (1649.683 us; speedup 1.0000x reference)
//
#include <hip/hip_runtime.h>
#include <cfloat>
#include <climits>
#include <cstdint>

#define B_ 16
#define T_ 4096
#define D_ 256
#define K_ 1024
#define BT_ 65536
#define DECAYF 0.99f
#define OMDECAYF 0.01f
#define EPSF 1e-5f
#define TAUGAP 0.125f

// ---------------- zero workspace ----------------
__global__ void k_zero(uint32_t* __restrict__ p, int n) {
    int i = blockIdx.x * blockDim.x + threadIdx.x;
    if (i < n) p[i] = 0u;
}

// ---------------- ||e_k||^2 ----------------
__global__ void k_enorm(const float* __restrict__ E, float* __restrict__ enorm) {
    int k = blockIdx.x * 256 + threadIdx.x;  // grid 4
    float s = 0.f;
    for (int d = 0; d < D_; ++d) {
        float v = E[(size_t)d * K_ + k];
        s = fmaf(v, v, s);
    }
    enorm[k] = s;
}

// ---------------- fp32 argmin with top-2 gap tracking ----------------
// block: 256 threads (16x16), 64 rows per block, all K=1024 cols in 16 chunks of 64
__global__ __launch_bounds__(256, 2) void k_argmin(
    const float* __restrict__ z, const float* __restrict__ E,
    const float* __restrict__ enorm, int* __restrict__ code,
    int* __restrict__ flags, int* __restrict__ nflag) {
    __shared__ float zt[64][260];   // 66560 B, pad 4 -> 2-way bank conflicts only
    __shared__ float et[32][68];    // 8704 B
    const int t = threadIdx.x;
    const int tx = t & 15, ty = t >> 4;
    const int row0 = blockIdx.x * 64;

    // stage the 64x256 z tile (contiguous 64KB) as float4
    const float* zblk = z + (size_t)row0 * D_;
    for (int j = 0; j < 16; ++j) {
        int v = j * 256 + t;          // float4 index 0..4095
        int flat = v * 4;
        int r = flat >> 8, dc = flat & 255;
        float4 val = *(const float4*)(zblk + flat);
        *(float4*)&zt[r][dc] = val;
    }

    float d1[4] = {FLT_MAX, FLT_MAX, FLT_MAX, FLT_MAX};
    float d2[4] = {FLT_MAX, FLT_MAX, FLT_MAX, FLT_MAX};
    int   i1[4] = {INT_MAX, INT_MAX, INT_MAX, INT_MAX};

    for (int kc = 0; kc < 16; ++kc) {
        float acc[4][4];
        #pragma unroll
        for (int a = 0; a < 4; ++a)
            #pragma unroll
            for (int b = 0; b < 4; ++b) acc[a][b] = 0.f;

        for (int dc = 0; dc < 8; ++dc) {
            __syncthreads();
            // stage E chunk [32 d][64 c], coalesced global reads
            for (int j = 0; j < 8; ++j) {
                int f = j * 256 + t;
                int dr = f >> 6, c = f & 63;
                et[dr][c] = E[(size_t)(dc * 32 + dr) * K_ + kc * 64 + c];
            }
            __syncthreads();
            #pragma unroll
            for (int q = 0; q < 8; ++q) {
                int dbase = dc * 32 + q * 4;
                float4 zf[4], ef[4];
                #pragma unroll
                for (int ri = 0; ri < 4; ++ri) zf[ri] = *(const float4*)&zt[4 * ty + ri][dbase];
                #pragma unroll
                for (int di = 0; di < 4; ++di) ef[di] = *(const float4*)&et[q * 4 + di][4 * tx];
                #pragma unroll
                for (int ri = 0; ri < 4; ++ri) {
                    #pragma unroll
                    for (int di = 0; di < 4; ++di) {
                        float zv = ((const float*)&zf[ri])[di];
                        acc[ri][0] = fmaf(zv, ef[di].x, acc[ri][0]);
                        acc[ri][1] = fmaf(zv, ef[di].y, acc[ri][1]);
                        acc[ri][2] = fmaf(zv, ef[di].z, acc[ri][2]);
                        acc[ri][3] = fmaf(zv, ef[di].w, acc[ri][3]);
                    }
                }
            }
        }
        // fold this column chunk into per-thread top-2
        #pragma unroll
        for (int ri = 0; ri < 4; ++ri) {
            #pragma unroll
            for (int ci = 0; ci < 4; ++ci) {
                int cg = kc * 64 + 4 * tx + ci;
                float dist = enorm[cg] - 2.0f * acc[ri][ci];
                if (dist < d1[ri] || (dist == d1[ri] && cg < i1[ri])) {
                    d2[ri] = d1[ri]; d1[ri] = dist; i1[ri] = cg;
                } else if (dist < d2[ri]) {
                    d2[ri] = dist;
                }
            }
        }
    }

    // cross-thread (16 tx slices) top-2 merge per row, reusing zt storage
    __syncthreads();
    float* redd1 = &zt[0][0];
    int*   redi1 = (int*)(redd1 + 1024);
    float* redd2 = (float*)(redi1 + 1024);
    #pragma unroll
    for (int ri = 0; ri < 4; ++ri) {
        int r = 4 * ty + ri;
        redd1[r * 16 + tx] = d1[ri];
        redi1[r * 16 + tx] = i1[ri];
        redd2[r * 16 + tx] = d2[ri];
    }
    __syncthreads();
    if (t < 64) {
        float b1 = FLT_MAX, b2 = FLT_MAX; int bi = INT_MAX;
        for (int j = 0; j < 16; ++j) {
            float a1 = redd1[t * 16 + j];
            int   ai = redi1[t * 16 + j];
            float a2 = redd2[t * 16 + j];
            if (a1 < b1 || (a1 == b1 && ai < bi)) {
                b2 = fminf(b1, a2); b1 = a1; bi = ai;
            } else {
                b2 = fminf(b2, a1);
            }
        }
        code[row0 + t] = bi;
        if (b2 - b1 < TAUGAP) {      // near-tie: re-resolve in fp64
            int pos = atomicAdd(nflag, 1);
            flags[pos] = row0 + t;
        }
    }
}

// ---------------- fp64 exact re-resolution of flagged rows ----------------
__global__ void k_fixup(const float* __restrict__ z, const float* __restrict__ E,
                        const int* __restrict__ nflag, const int* __restrict__ flags,
                        int* __restrict__ code) {
    __shared__ double sd[256];
    __shared__ int    si[256];
    __shared__ float  zr[256];
    int n = *nflag;
    for (int f = blockIdx.x; f < n; f += gridDim.x) {
        int row = flags[f];
        __syncthreads();
        zr[threadIdx.x] = z[(size_t)row * D_ + threadIdx.x];
        __syncthreads();
        double bd = DBL_MAX; int bi = INT_MAX;
        for (int j = 0; j < 4; ++j) {
            int c = threadIdx.x + j * 256;
            double dot = 0.0, e2 = 0.0;
            for (int d = 0; d < D_; ++d) {
                double ev = (double)E[(size_t)d * K_ + c];
                e2  = fma(ev, ev, e2);
                dot = fma((double)zr[d], ev, dot);
            }
            double dist = e2 - 2.0 * dot;
            if (dist < bd || (dist == bd && c < bi)) { bd = dist; bi = c; }
        }
        sd[threadIdx.x] = bd; si[threadIdx.x] = bi;
        __syncthreads();
        for (int s = 128; s > 0; s >>= 1) {
            if (threadIdx.x < s) {
                double od = sd[threadIdx.x + s]; int oi = si[threadIdx.x + s];
                if (od < sd[threadIdx.x] || (od == sd[threadIdx.x] && oi < si[threadIdx.x])) {
                    sd[threadIdx.x] = od; si[threadIdx.x] = oi;
                }
            }
            __syncthreads();
        }
        if (threadIdx.x == 0) code[row] = si[0];
    }
}

// ---------------- scatter: counts + emb_sum[K][D] ----------------
__global__ void k_scatter(const float* __restrict__ z, const int* __restrict__ code,
                          int* __restrict__ counts, float* __restrict__ emb_sum) {
    int w = threadIdx.x >> 6;   // wave in block
    int l = threadIdx.x & 63;
    int row = blockIdx.x * 4 + w;
    int idx = code[row];
    float4 v = *(const float4*)(z + (size_t)row * D_ + l * 4);
    float* dst = emb_sum + (size_t)idx * D_ + l * 4;
    atomicAdd(dst + 0, v.x);
    atomicAdd(dst + 1, v.y);
    atomicAdd(dst + 2, v.z);
    atomicAdd(dst + 3, v.w);
    if (l == 0) atomicAdd(counts + idx, 1);
}

// ---------------- cluster-size EMA + Laplace norm ----------------
__global__ void k_cs(const float* __restrict__ cs, const int* __restrict__ counts,
                     float* __restrict__ out_newcs, float* __restrict__ csnorm) {
    __shared__ float red[1024];
    int k = threadIdx.x;
    float ncs = cs[k] * DECAYF + OMDECAYF * (float)counts[k];
    out_newcs[k] = ncs;
    red[k] = ncs;
    __syncthreads();
    for (int s = 512; s > 0; s >>= 1) {
        if (k < s) red[k] += red[k + s];
        __syncthreads();
    }
    float n = red[0];
    csnorm[k] = (ncs + EPSF) / (n + (float)K_ * EPSF) * n;
}

// ---------------- embedding-mean EMA + normalized codebook ----------------
__global__ void k_emb(const float* __restrict__ EM, const float* __restrict__ emb_sum,
                      const float* __restrict__ csnorm,
                      float* __restrict__ out_newemb, float* __restrict__ out_newem,
                      float* __restrict__ newembT) {
    int tid = blockIdx.x * 256 + threadIdx.x;  // grid 1024, tid = k*256+d
    int k = tid >> 8, d = tid & 255;
    float em  = EM[(size_t)d * K_ + k];
    float nem = em * DECAYF + OMDECAYF * emb_sum[tid];
    float nq  = nem / csnorm[k];
    out_newem [(size_t)d * K_ + k] = nem;
    out_newemb[(size_t)d * K_ + k] = nq;
    newembT[tid] = nq;   // [K][D] copy for contiguous gather
}

// ---------------- gather z_q + code + per-block loss partials ----------------
__global__ void k_gather(const float* __restrict__ z, const int* __restrict__ code,
                         const float* __restrict__ newembT,
                         float* __restrict__ out_zq, float* __restrict__ out_code,
                         double* __restrict__ partial) {
    __shared__ double wsum[4];
    int w = threadIdx.x >> 6, l = threadIdx.x & 63;
    int row = blockIdx.x * 4 + w;
    int idx = code[row];
    float4 zv = *(const float4*)(z + (size_t)row * D_ + l * 4);
    float4 ev = *(const float4*)(newembT + (size_t)idx * D_ + l * 4);
    *(float4*)(out_zq + (size_t)row * D_ + l * 4) = ev;
    if (l == 0) out_code[row] = (float)idx;
    float dx = ev.x - zv.x, dy = ev.y - zv.y, dz = ev.z - zv.z, dw = ev.w - zv.w;
    double s = (double)dx * dx + (double)dy * dy + (double)dz * dz + (double)dw * dw;
    for (int off = 32; off > 0; off >>= 1) s += __shfl_down(s, off);
    if (l == 0) wsum[w] = s;
    __syncthreads();
    if (threadIdx.x == 0) partial[blockIdx.x] = wsum[0] + wsum[1] + wsum[2] + wsum[3];
}

// ---------------- finalize losses ----------------
__global__ void k_final(const double* __restrict__ partial, float* __restrict__ out_closs,
                        float* __restrict__ out_cbloss) {
    __shared__ double red[256];
    int b = blockIdx.x;  // 16
    double s = 0.0;
    for (int j = threadIdx.x; j < 1024; j += 256) s += partial[b * 1024 + j];
    red[threadIdx.x] = s;
    __syncthreads();
    for (int st = 128; st > 0; st >>= 1) {
        if (threadIdx.x < st) red[threadIdx.x] += red[threadIdx.x + st];
        __syncthreads();
    }
    if (threadIdx.x == 0) {
        out_closs[b]  = (float)(red[0] / (double)((size_t)T_ * D_));
        out_cbloss[b] = 0.0f;
    }
}

extern "C" void kernel_launch(void* const* d_in, const int* in_sizes, int n_in,
                              void* d_out, int out_size, void* d_ws, size_t ws_size,
                              hipStream_t stream) {
    (void)in_sizes; (void)n_in; (void)out_size; (void)ws_size;
    const float* z  = (const float*)d_in[0];
    const float* E  = (const float*)d_in[1];
    const float* cs = (const float*)d_in[2];
    const float* EM = (const float*)d_in[3];

    float* out       = (float*)d_out;
    float* out_zq    = out;                         // 16777216
    float* out_closs = out + 16777216;              // 16
    float* out_cbl   = out_closs + 16;              // 16
    float* out_code  = out_cbl + 16;                // 65536
    float* out_nemb  = out_code + 65536;            // 262144
    float* out_ncs   = out_nemb + 262144;           // 1024
    float* out_nem   = out_ncs + 1024;              // 262144

    char* w = (char*)d_ws;
    int*    counts  = (int*)(w + 0);                // 4096 B  (zeroed)
    int*    nflag   = (int*)(w + 4096);             // 64 B    (zeroed)
    double* partial = (double*)(w + 4160);          // 131072 B (zeroed, 8B aligned)
    float*  emb_sum = (float*)(w + 135232);         // 1048576 B (zeroed)
    float*  enorm   = (float*)(w + 1183808);        // 4096 B
    int*    code_i  = (int*)(w + 1187904);          // 262144 B
    int*    flags   = (int*)(w + 1450048);          // 262144 B
    float*  csnorm  = (float*)(w + 1712192);        // 4096 B
    float*  newembT = (float*)(w + 1716352);        // 1048576 B   (end ~2.76 MB)

    // zero the accumulation zone [0, 1183808)
    {
        int nwords = 1183808 / 4;
        k_zero<<<(nwords + 255) / 256, 256, 0, stream>>>((uint32_t*)d_ws, nwords);
    }
    k_enorm  <<<K_ / 256, 256, 0, stream>>>(E, enorm);
    k_argmin <<<BT_ / 64, 256, 0, stream>>>(z, E, enorm, code_i, flags, nflag);
    k_fixup  <<<256, 256, 0, stream>>>(z, E, nflag, flags, code_i);
    k_scatter<<<BT_ / 4, 256, 0, stream>>>(z, code_i, counts, emb_sum);
    k_cs     <<<1, 1024, 0, stream>>>(cs, counts, out_ncs, csnorm);
    k_emb    <<<(K_ * D_) / 256, 256, 0, stream>>>(EM, emb_sum, csnorm, out_nemb, out_nem, newembT);
    k_gather <<<BT_ / 4, 256, 0, stream>>>(z, code_i, newembT, out_zq, out_code, partial);
    k_final  <<<B_, 256, 0, stream>>>(partial, out_closs, out_cbl);
}

// Round 2
// 989.296 us; speedup vs baseline: 1.6675x; 1.6675x over previous
//
#include <hip/hip_runtime.h>
#include <cfloat>
#include <climits>
#include <cstdint>

#define B_ 16
#define T_ 4096
#define D_ 256
#define K_ 1024
#define BT_ 65536
#define DECAYF 0.99f
#define OMDECAYF 0.01f
#define EPSF 1e-5f
#define TAUGAP 0.125f

typedef unsigned short u16;
typedef short bf16x8 __attribute__((ext_vector_type(8)));
typedef float f32x4 __attribute__((ext_vector_type(4)));

__device__ __forceinline__ u16 f2bf(float f) {
    unsigned u = __float_as_uint(f);
    unsigned r = (u + 0x7fffu + ((u >> 16) & 1u)) >> 16;
    return (u16)r;
}
__device__ __forceinline__ float bf2f(u16 b) {
    return __uint_as_float(((unsigned)b) << 16);
}
__device__ __forceinline__ void gload16(const void* g, void* l) {
    __builtin_amdgcn_global_load_lds(
        (const __attribute__((address_space(1))) void*)g,
        (__attribute__((address_space(3))) void*)l, 16, 0, 0);
}

// ---------------- zero workspace ----------------
__global__ void k_zero(uint32_t* __restrict__ p, int n) {
    int i = blockIdx.x * blockDim.x + threadIdx.x;
    if (i < n) p[i] = 0u;
}

// ---------------- split z into bf16 hi/lo ----------------
__global__ void k_split_z(const float* __restrict__ z, u16* __restrict__ zh,
                          u16* __restrict__ zl) {
    int base = (blockIdx.x * 256 + threadIdx.x) * 8;
    float4 v0 = *(const float4*)(z + base);
    float4 v1 = *(const float4*)(z + base + 4);
    float f[8] = {v0.x, v0.y, v0.z, v0.w, v1.x, v1.y, v1.z, v1.w};
    u16 h[8], lo[8];
    #pragma unroll
    for (int j = 0; j < 8; ++j) {
        h[j] = f2bf(f[j]);
        lo[j] = f2bf(f[j] - bf2f(h[j]));
    }
    typedef u16 u16x8 __attribute__((ext_vector_type(8)));
    u16x8 hv, lv;
    #pragma unroll
    for (int j = 0; j < 8; ++j) { hv[j] = h[j]; lv[j] = lo[j]; }
    *(u16x8*)(zh + base) = hv;
    *(u16x8*)(zl + base) = lv;
}

// ---------------- split+transpose E, fp64 enorm ----------------
__global__ void k_prepE(const float* __restrict__ E, u16* __restrict__ EhT,
                        u16* __restrict__ ElT, float* __restrict__ enorm) {
    __shared__ double rd[256];
    int n = blockIdx.x, d = threadIdx.x;
    float v = E[(size_t)d * K_ + n];
    u16 hb = f2bf(v);
    u16 lb = f2bf(v - bf2f(hb));
    EhT[(size_t)n * D_ + d] = hb;
    ElT[(size_t)n * D_ + d] = lb;
    rd[d] = (double)v * (double)v;
    __syncthreads();
    for (int s = 128; s > 0; s >>= 1) {
        if (d < s) rd[d] += rd[d + s];
        __syncthreads();
    }
    if (d == 0) enorm[n] = (float)rd[0];
}

// ---------------- MFMA distance GEMM + fused argmin top-2 ----------------
// grid 512 (row-blocks of 128), 512 threads (8 waves, 2x4 over M=128 x N=256)
// K-loop: 24 steps of BK=32 over [z_hi*E_hi | z_hi*E_lo | z_lo*E_hi]
__global__ __launch_bounds__(512, 2) void k_argmin_mfma(
    const u16* __restrict__ zh, const u16* __restrict__ zl,
    const u16* __restrict__ EhT, const u16* __restrict__ ElT,
    const float* __restrict__ enorm, int* __restrict__ code,
    int* __restrict__ flags, int* __restrict__ nflag) {
    __shared__ u16 Ab[2][128 * 32];   // 8KB x2
    __shared__ u16 Bb[2][256 * 32];   // 16KB x2
    __shared__ float mg_d1[512];
    __shared__ int   mg_i1[512];
    __shared__ float mg_d2[512];

    const int t = threadIdx.x;
    const int row0 = blockIdx.x * 128;
    const int l = t & 63;
    const int wid = t >> 6;
    const int wr = wid >> 2, wc = wid & 3;
    const int lr = l & 15, lk = l >> 4;

    // staging indices: LDS tile is [rows][32 k] with 16B-block XOR swizzle
    // phys_blk = logical_blk ^ ((row>>1)&3); dest linear (global_load_lds),
    // so the inverse permutation is applied to the GLOBAL source address.
    const int arow = t >> 2;
    const int ablk = (t & 3) ^ ((arow >> 1) & 3);
    const int brow0 = t >> 2;
    const int bblk0 = (t & 3) ^ ((brow0 >> 1) & 3);
    const int brow1 = (t + 512) >> 2;
    const int bblk1 = ((t + 512) & 3) ^ ((brow1 >> 1) & 3);

    float D1 = FLT_MAX, D2 = FLT_MAX;
    int I1 = 0x7fffffff;

#define STAGE(nc_, ks_, buf_) do {                                          \
        int p_ = (ks_) >> 3;                                                 \
        const u16* Za_ = (p_ == 2) ? zl : zh;                                \
        const u16* Eb_ = (p_ == 1) ? ElT : EhT;                              \
        int kb_ = ((ks_) & 7) * 32;                                          \
        gload16(Za_ + (size_t)(row0 + arow) * D_ + kb_ + ablk * 8,           \
                &Ab[buf_][(t & ~63) * 8]);                                   \
        gload16(Eb_ + (size_t)((nc_) * 256 + brow0) * D_ + kb_ + bblk0 * 8,  \
                &Bb[buf_][(t & ~63) * 8]);                                   \
        gload16(Eb_ + (size_t)((nc_) * 256 + brow1) * D_ + kb_ + bblk1 * 8,  \
                &Bb[buf_][((t + 512) & ~63) * 8]);                           \
    } while (0)

    for (int nc = 0; nc < 4; ++nc) {
        f32x4 acc[4][4];
        #pragma unroll
        for (int m = 0; m < 4; ++m)
            #pragma unroll
            for (int n = 0; n < 4; ++n) acc[m][n] = (f32x4){0.f, 0.f, 0.f, 0.f};

        STAGE(nc, 0, 0);
        for (int ks = 0; ks < 24; ++ks) {
            __syncthreads();               // drains vmcnt: buf[ks&1] ready
            if (ks + 1 < 24) STAGE(nc, ks + 1, (ks + 1) & 1);
            const u16* Abuf = Ab[ks & 1];
            const u16* Bbuf = Bb[ks & 1];
            bf16x8 a[4], b[4];
            #pragma unroll
            for (int m = 0; m < 4; ++m) {
                int row = wr * 64 + m * 16 + lr;
                a[m] = *(const bf16x8*)&Abuf[row * 32 + ((lk ^ ((row >> 1) & 3)) * 8)];
            }
            #pragma unroll
            for (int n = 0; n < 4; ++n) {
                int nn = wc * 64 + n * 16 + lr;
                b[n] = *(const bf16x8*)&Bbuf[nn * 32 + ((lk ^ ((nn >> 1) & 3)) * 8)];
            }
            #pragma unroll
            for (int m = 0; m < 4; ++m)
                #pragma unroll
                for (int n = 0; n < 4; ++n)
                    acc[m][n] = __builtin_amdgcn_mfma_f32_16x16x32_bf16(
                        a[m], b[n], acc[m][n], 0, 0, 0);
        }
        __syncthreads();   // all ds_reads done before epilogue / next stage

        // ---- epilogue: dist = enorm - 2*acc, fold top-2 per row ----
        float en[4];
        #pragma unroll
        for (int n = 0; n < 4; ++n)
            en[n] = enorm[nc * 256 + wc * 64 + n * 16 + lr];

        #pragma unroll
        for (int m = 0; m < 4; ++m) {
            #pragma unroll
            for (int r = 0; r < 4; ++r) {
                float d1 = FLT_MAX, d2 = FLT_MAX;
                int i1 = 0x7fffffff;
                #pragma unroll
                for (int n = 0; n < 4; ++n) {
                    float dist = en[n] - 2.0f * acc[m][n][r];
                    int cg = nc * 256 + wc * 64 + n * 16 + lr;
                    if (dist < d1) { d2 = d1; d1 = dist; i1 = cg; }
                    else d2 = fminf(d2, dist);
                }
                // merge across the 16 lanes (lr) holding this row
                #pragma unroll
                for (int mask = 1; mask < 16; mask <<= 1) {
                    float pd1 = __shfl_xor(d1, mask);
                    int   pi1 = __shfl_xor(i1, mask);
                    float pd2 = __shfl_xor(d2, mask);
                    if (pd1 < d1 || (pd1 == d1 && pi1 < i1)) {
                        d2 = fminf(d1, pd2); d1 = pd1; i1 = pi1;
                    } else d2 = fminf(d2, pd1);
                }
                if (lr == 0) {
                    int row = wr * 64 + m * 16 + lk * 4 + r;  // C/D: row=(lane>>4)*4+reg
                    mg_d1[row * 4 + wc] = d1;
                    mg_i1[row * 4 + wc] = i1;
                    mg_d2[row * 4 + wc] = d2;
                }
            }
        }
        __syncthreads();
        if (t < 128) {
            #pragma unroll
            for (int c = 0; c < 4; ++c) {
                float pd1 = mg_d1[t * 4 + c];
                int   pi1 = mg_i1[t * 4 + c];
                float pd2 = mg_d2[t * 4 + c];
                if (pd1 < D1 || (pd1 == D1 && pi1 < I1)) {
                    D2 = fminf(D1, pd2); D1 = pd1; I1 = pi1;
                } else D2 = fminf(D2, pd1);
            }
        }
        __syncthreads();
    }
#undef STAGE

    if (t < 128) {
        code[row0 + t] = I1;
        if (D2 - D1 < TAUGAP) {
            int pos = atomicAdd(nflag, 1);
            flags[pos] = row0 + t;
        }
    }
}

// ---------------- fp64 exact re-resolution of flagged rows ----------------
__global__ void k_fixup(const float* __restrict__ z, const float* __restrict__ E,
                        const int* __restrict__ nflag, const int* __restrict__ flags,
                        int* __restrict__ code) {
    __shared__ double sd[256];
    __shared__ int    si[256];
    __shared__ float  zr[256];
    int n = *nflag;
    for (int f = blockIdx.x; f < n; f += gridDim.x) {
        int row = flags[f];
        __syncthreads();
        zr[threadIdx.x] = z[(size_t)row * D_ + threadIdx.x];
        __syncthreads();
        double bd = DBL_MAX; int bi = INT_MAX;
        for (int j = 0; j < 4; ++j) {
            int c = threadIdx.x + j * 256;
            double dot = 0.0, e2 = 0.0;
            for (int d = 0; d < D_; ++d) {
                double ev = (double)E[(size_t)d * K_ + c];
                e2  = fma(ev, ev, e2);
                dot = fma((double)zr[d], ev, dot);
            }
            double dist = e2 - 2.0 * dot;
            if (dist < bd || (dist == bd && c < bi)) { bd = dist; bi = c; }
        }
        sd[threadIdx.x] = bd; si[threadIdx.x] = bi;
        __syncthreads();
        for (int s = 128; s > 0; s >>= 1) {
            if (threadIdx.x < s) {
                double od = sd[threadIdx.x + s]; int oi = si[threadIdx.x + s];
                if (od < sd[threadIdx.x] || (od == sd[threadIdx.x] && oi < si[threadIdx.x])) {
                    sd[threadIdx.x] = od; si[threadIdx.x] = oi;
                }
            }
            __syncthreads();
        }
        if (threadIdx.x == 0) code[row] = si[0];
    }
}

// ---------------- scatter: counts + emb_sum[K][D] ----------------
__global__ void k_scatter(const float* __restrict__ z, const int* __restrict__ code,
                          int* __restrict__ counts, float* __restrict__ emb_sum) {
    int w = threadIdx.x >> 6;
    int l = threadIdx.x & 63;
    int row = blockIdx.x * 4 + w;
    int idx = code[row];
    float4 v = *(const float4*)(z + (size_t)row * D_ + l * 4);
    float* dst = emb_sum + (size_t)idx * D_ + l * 4;
    atomicAdd(dst + 0, v.x);
    atomicAdd(dst + 1, v.y);
    atomicAdd(dst + 2, v.z);
    atomicAdd(dst + 3, v.w);
    if (l == 0) atomicAdd(counts + idx, 1);
}

// ---------------- cluster-size EMA + Laplace norm ----------------
__global__ void k_cs(const float* __restrict__ cs, const int* __restrict__ counts,
                     float* __restrict__ out_newcs, float* __restrict__ csnorm) {
    __shared__ float red[1024];
    int k = threadIdx.x;
    float ncs = cs[k] * DECAYF + OMDECAYF * (float)counts[k];
    out_newcs[k] = ncs;
    red[k] = ncs;
    __syncthreads();
    for (int s = 512; s > 0; s >>= 1) {
        if (k < s) red[k] += red[k + s];
        __syncthreads();
    }
    float n = red[0];
    csnorm[k] = (ncs + EPSF) / (n + (float)K_ * EPSF) * n;
}

// ---------------- embedding-mean EMA + normalized codebook ----------------
__global__ void k_emb(const float* __restrict__ EM, const float* __restrict__ emb_sum,
                      const float* __restrict__ csnorm,
                      float* __restrict__ out_newemb, float* __restrict__ out_newem,
                      float* __restrict__ newembT) {
    int tid = blockIdx.x * 256 + threadIdx.x;
    int k = tid >> 8, d = tid & 255;
    float em  = EM[(size_t)d * K_ + k];
    float nem = em * DECAYF + OMDECAYF * emb_sum[tid];
    float nq  = nem / csnorm[k];
    out_newem [(size_t)d * K_ + k] = nem;
    out_newemb[(size_t)d * K_ + k] = nq;
    newembT[tid] = nq;
}

// ---------------- gather z_q + code + per-block loss partials ----------------
__global__ void k_gather(const float* __restrict__ z, const int* __restrict__ code,
                         const float* __restrict__ newembT,
                         float* __restrict__ out_zq, float* __restrict__ out_code,
                         double* __restrict__ partial) {
    __shared__ double wsum[4];
    int w = threadIdx.x >> 6, l = threadIdx.x & 63;
    int row = blockIdx.x * 4 + w;
    int idx = code[row];
    float4 zv = *(const float4*)(z + (size_t)row * D_ + l * 4);
    float4 ev = *(const float4*)(newembT + (size_t)idx * D_ + l * 4);
    *(float4*)(out_zq + (size_t)row * D_ + l * 4) = ev;
    if (l == 0) out_code[row] = (float)idx;
    float dx = ev.x - zv.x, dy = ev.y - zv.y, dz = ev.z - zv.z, dw = ev.w - zv.w;
    double s = (double)dx * dx + (double)dy * dy + (double)dz * dz + (double)dw * dw;
    for (int off = 32; off > 0; off >>= 1) s += __shfl_down(s, off);
    if (l == 0) wsum[w] = s;
    __syncthreads();
    if (threadIdx.x == 0) partial[blockIdx.x] = wsum[0] + wsum[1] + wsum[2] + wsum[3];
}

// ---------------- finalize losses ----------------
__global__ void k_final(const double* __restrict__ partial, float* __restrict__ out_closs,
                        float* __restrict__ out_cbloss) {
    __shared__ double red[256];
    int b = blockIdx.x;
    double s = 0.0;
    for (int j = threadIdx.x; j < 1024; j += 256) s += partial[b * 1024 + j];
    red[threadIdx.x] = s;
    __syncthreads();
    for (int st = 128; st > 0; st >>= 1) {
        if (threadIdx.x < st) red[threadIdx.x] += red[threadIdx.x + st];
        __syncthreads();
    }
    if (threadIdx.x == 0) {
        out_closs[b]  = (float)(red[0] / (double)((size_t)T_ * D_));
        out_cbloss[b] = 0.0f;
    }
}

extern "C" void kernel_launch(void* const* d_in, const int* in_sizes, int n_in,
                              void* d_out, int out_size, void* d_ws, size_t ws_size,
                              hipStream_t stream) {
    (void)in_sizes; (void)n_in; (void)out_size; (void)ws_size;
    const float* z  = (const float*)d_in[0];
    const float* E  = (const float*)d_in[1];
    const float* cs = (const float*)d_in[2];
    const float* EM = (const float*)d_in[3];

    float* out       = (float*)d_out;
    float* out_zq    = out;                         // 16777216 floats
    float* out_closs = out + 16777216;              // 16
    float* out_cbl   = out_closs + 16;              // 16
    float* out_code  = out_cbl + 16;                // 65536
    float* out_nemb  = out_code + 65536;            // 262144
    float* out_ncs   = out_nemb + 262144;           // 1024
    float* out_nem   = out_ncs + 1024;              // 262144

    // z_hi / z_lo live in the z_q output region (fully overwritten by k_gather)
    u16* zh = (u16*)out_zq;                 // 16777216 u16 = 32MB
    u16* zl = (u16*)(out_zq + 8388608);     // next 32MB

    char* w = (char*)d_ws;
    int*    counts  = (int*)(w + 0);                // 4096 B  (zeroed)
    int*    nflag   = (int*)(w + 4096);             // 64 B    (zeroed)
    double* partial = (double*)(w + 4160);          // 131072 B
    float*  emb_sum = (float*)(w + 135232);         // 1048576 B (zeroed)
    float*  enorm   = (float*)(w + 1183808);        // 4096 B
    int*    code_i  = (int*)(w + 1187904);          // 262144 B
    int*    flags   = (int*)(w + 1450048);          // 262144 B
    float*  csnorm  = (float*)(w + 1712192);        // 4096 B
    float*  newembT = (float*)(w + 1716352);        // 1048576 B
    u16*    EhT     = (u16*)(w + 2764928);          // 524288 B
    u16*    ElT     = (u16*)(w + 3289216);          // 524288 B  (end ~3.64 MB)

    {   // zero counts/nflag/partial/emb_sum
        int nwords = 1183808 / 4;
        k_zero<<<(nwords + 255) / 256, 256, 0, stream>>>((uint32_t*)d_ws, nwords);
    }
    k_split_z<<<BT_ * D_ / (256 * 8), 256, 0, stream>>>(z, zh, zl);
    k_prepE  <<<K_, 256, 0, stream>>>(E, EhT, ElT, enorm);
    k_argmin_mfma<<<BT_ / 128, 512, 0, stream>>>(zh, zl, EhT, ElT, enorm,
                                                 code_i, flags, nflag);
    k_fixup  <<<256, 256, 0, stream>>>(z, E, nflag, flags, code_i);
    k_scatter<<<BT_ / 4, 256, 0, stream>>>(z, code_i, counts, emb_sum);
    k_cs     <<<1, 1024, 0, stream>>>(cs, counts, out_ncs, csnorm);
    k_emb    <<<(K_ * D_) / 256, 256, 0, stream>>>(EM, emb_sum, csnorm,
                                                   out_nemb, out_nem, newembT);
    k_gather <<<BT_ / 4, 256, 0, stream>>>(z, code_i, newembT, out_zq, out_code, partial);
    k_final  <<<B_, 256, 0, stream>>>(partial, out_closs, out_cbl);
}

// Round 3
// 695.420 us; speedup vs baseline: 2.3722x; 1.4226x over previous
//
#include <hip/hip_runtime.h>
#include <cfloat>
#include <climits>
#include <cstdint>

#define B_ 16
#define T_ 4096
#define D_ 256
#define K_ 1024
#define BT_ 65536
#define DECAYF 0.99f
#define OMDECAYF 0.01f
#define EPSF 1e-5f
#define TAUGAP 0.125f

typedef unsigned short u16;
typedef short bf16x8 __attribute__((ext_vector_type(8)));
typedef float f32x4 __attribute__((ext_vector_type(4)));

__device__ __forceinline__ u16 f2bf(float f) {
    unsigned u = __float_as_uint(f);
    unsigned r = (u + 0x7fffu + ((u >> 16) & 1u)) >> 16;
    return (u16)r;
}
__device__ __forceinline__ float bf2f(u16 b) {
    return __uint_as_float(((unsigned)b) << 16);
}
__device__ __forceinline__ void gload16(const void* g, void* l) {
    __builtin_amdgcn_global_load_lds(
        (const __attribute__((address_space(1))) void*)g,
        (__attribute__((address_space(3))) void*)l, 16, 0, 0);
}

// ---------------- zero (counts + nflag only) ----------------
__global__ void k_zero(uint32_t* __restrict__ p, int n) {
    int i = blockIdx.x * blockDim.x + threadIdx.x;
    if (i < n) p[i] = 0u;
}

// ---------------- split z into bf16 hi/lo ----------------
__global__ void k_split_z(const float* __restrict__ z, u16* __restrict__ zh,
                          u16* __restrict__ zl) {
    int base = (blockIdx.x * 256 + threadIdx.x) * 8;
    float4 v0 = *(const float4*)(z + base);
    float4 v1 = *(const float4*)(z + base + 4);
    float f[8] = {v0.x, v0.y, v0.z, v0.w, v1.x, v1.y, v1.z, v1.w};
    u16 h[8], lo[8];
    #pragma unroll
    for (int j = 0; j < 8; ++j) {
        h[j] = f2bf(f[j]);
        lo[j] = f2bf(f[j] - bf2f(h[j]));
    }
    typedef u16 u16x8 __attribute__((ext_vector_type(8)));
    u16x8 hv, lv;
    #pragma unroll
    for (int j = 0; j < 8; ++j) { hv[j] = h[j]; lv[j] = lo[j]; }
    *(u16x8*)(zh + base) = hv;
    *(u16x8*)(zl + base) = lv;
}

// ---------------- split+transpose E, fp64 enorm ----------------
__global__ void k_prepE(const float* __restrict__ E, u16* __restrict__ EhT,
                        u16* __restrict__ ElT, float* __restrict__ enorm) {
    __shared__ double rd[256];
    int n = blockIdx.x, d = threadIdx.x;
    float v = E[(size_t)d * K_ + n];
    u16 hb = f2bf(v);
    u16 lb = f2bf(v - bf2f(hb));
    EhT[(size_t)n * D_ + d] = hb;
    ElT[(size_t)n * D_ + d] = lb;
    rd[d] = (double)v * (double)v;
    __syncthreads();
    for (int s = 128; s > 0; s >>= 1) {
        if (d < s) rd[d] += rd[d + s];
        __syncthreads();
    }
    if (d == 0) enorm[n] = (float)rd[0];
}

// ---------------- MFMA distance GEMM + fused argmin top-2 ----------------
__global__ __launch_bounds__(512, 2) void k_argmin_mfma(
    const u16* __restrict__ zh, const u16* __restrict__ zl,
    const u16* __restrict__ EhT, const u16* __restrict__ ElT,
    const float* __restrict__ enorm, int* __restrict__ code,
    int* __restrict__ flags, int* __restrict__ nflag) {
    __shared__ u16 Ab[2][128 * 32];
    __shared__ u16 Bb[2][256 * 32];
    __shared__ float mg_d1[512];
    __shared__ int   mg_i1[512];
    __shared__ float mg_d2[512];

    const int t = threadIdx.x;
    const int row0 = blockIdx.x * 128;
    const int l = t & 63;
    const int wid = t >> 6;
    const int wr = wid >> 2, wc = wid & 3;
    const int lr = l & 15, lk = l >> 4;

    const int arow = t >> 2;
    const int ablk = (t & 3) ^ ((arow >> 1) & 3);
    const int brow0 = t >> 2;
    const int bblk0 = (t & 3) ^ ((brow0 >> 1) & 3);
    const int brow1 = (t + 512) >> 2;
    const int bblk1 = ((t + 512) & 3) ^ ((brow1 >> 1) & 3);

    float D1 = FLT_MAX, D2 = FLT_MAX;
    int I1 = 0x7fffffff;

#define STAGE(nc_, ks_, buf_) do {                                          \
        int p_ = (ks_) >> 3;                                                 \
        const u16* Za_ = (p_ == 2) ? zl : zh;                                \
        const u16* Eb_ = (p_ == 1) ? ElT : EhT;                              \
        int kb_ = ((ks_) & 7) * 32;                                          \
        gload16(Za_ + (size_t)(row0 + arow) * D_ + kb_ + ablk * 8,           \
                &Ab[buf_][(t & ~63) * 8]);                                   \
        gload16(Eb_ + (size_t)((nc_) * 256 + brow0) * D_ + kb_ + bblk0 * 8,  \
                &Bb[buf_][(t & ~63) * 8]);                                   \
        gload16(Eb_ + (size_t)((nc_) * 256 + brow1) * D_ + kb_ + bblk1 * 8,  \
                &Bb[buf_][((t + 512) & ~63) * 8]);                           \
    } while (0)

    for (int nc = 0; nc < 4; ++nc) {
        f32x4 acc[4][4];
        #pragma unroll
        for (int m = 0; m < 4; ++m)
            #pragma unroll
            for (int n = 0; n < 4; ++n) acc[m][n] = (f32x4){0.f, 0.f, 0.f, 0.f};

        STAGE(nc, 0, 0);
        for (int ks = 0; ks < 24; ++ks) {
            __syncthreads();
            if (ks + 1 < 24) STAGE(nc, ks + 1, (ks + 1) & 1);
            const u16* Abuf = Ab[ks & 1];
            const u16* Bbuf = Bb[ks & 1];
            bf16x8 a[4], b[4];
            #pragma unroll
            for (int m = 0; m < 4; ++m) {
                int row = wr * 64 + m * 16 + lr;
                a[m] = *(const bf16x8*)&Abuf[row * 32 + ((lk ^ ((row >> 1) & 3)) * 8)];
            }
            #pragma unroll
            for (int n = 0; n < 4; ++n) {
                int nn = wc * 64 + n * 16 + lr;
                b[n] = *(const bf16x8*)&Bbuf[nn * 32 + ((lk ^ ((nn >> 1) & 3)) * 8)];
            }
            #pragma unroll
            for (int m = 0; m < 4; ++m)
                #pragma unroll
                for (int n = 0; n < 4; ++n)
                    acc[m][n] = __builtin_amdgcn_mfma_f32_16x16x32_bf16(
                        a[m], b[n], acc[m][n], 0, 0, 0);
        }
        __syncthreads();

        float en[4];
        #pragma unroll
        for (int n = 0; n < 4; ++n)
            en[n] = enorm[nc * 256 + wc * 64 + n * 16 + lr];

        #pragma unroll
        for (int m = 0; m < 4; ++m) {
            #pragma unroll
            for (int r = 0; r < 4; ++r) {
                float d1 = FLT_MAX, d2 = FLT_MAX;
                int i1 = 0x7fffffff;
                #pragma unroll
                for (int n = 0; n < 4; ++n) {
                    float dist = en[n] - 2.0f * acc[m][n][r];
                    int cg = nc * 256 + wc * 64 + n * 16 + lr;
                    if (dist < d1) { d2 = d1; d1 = dist; i1 = cg; }
                    else d2 = fminf(d2, dist);
                }
                #pragma unroll
                for (int mask = 1; mask < 16; mask <<= 1) {
                    float pd1 = __shfl_xor(d1, mask);
                    int   pi1 = __shfl_xor(i1, mask);
                    float pd2 = __shfl_xor(d2, mask);
                    if (pd1 < d1 || (pd1 == d1 && pi1 < i1)) {
                        d2 = fminf(d1, pd2); d1 = pd1; i1 = pi1;
                    } else d2 = fminf(d2, pd1);
                }
                if (lr == 0) {
                    int row = wr * 64 + m * 16 + lk * 4 + r;
                    mg_d1[row * 4 + wc] = d1;
                    mg_i1[row * 4 + wc] = i1;
                    mg_d2[row * 4 + wc] = d2;
                }
            }
        }
        __syncthreads();
        if (t < 128) {
            #pragma unroll
            for (int c = 0; c < 4; ++c) {
                float pd1 = mg_d1[t * 4 + c];
                int   pi1 = mg_i1[t * 4 + c];
                float pd2 = mg_d2[t * 4 + c];
                if (pd1 < D1 || (pd1 == D1 && pi1 < I1)) {
                    D2 = fminf(D1, pd2); D1 = pd1; I1 = pi1;
                } else D2 = fminf(D2, pd1);
            }
        }
        __syncthreads();
    }
#undef STAGE

    if (t < 128) {
        code[row0 + t] = I1;
        if (D2 - D1 < TAUGAP) {
            int pos = atomicAdd(nflag, 1);
            flags[pos] = row0 + t;
        }
    }
}

// ---------------- fp64 exact re-resolution of flagged rows ----------------
__global__ void k_fixup(const float* __restrict__ z, const float* __restrict__ E,
                        const int* __restrict__ nflag, const int* __restrict__ flags,
                        int* __restrict__ code) {
    __shared__ double sd[256];
    __shared__ int    si[256];
    __shared__ float  zr[256];
    int n = *nflag;
    for (int f = blockIdx.x; f < n; f += gridDim.x) {
        int row = flags[f];
        __syncthreads();
        zr[threadIdx.x] = z[(size_t)row * D_ + threadIdx.x];
        __syncthreads();
        double bd = DBL_MAX; int bi = INT_MAX;
        for (int j = 0; j < 4; ++j) {
            int c = threadIdx.x + j * 256;
            double dot = 0.0, e2 = 0.0;
            for (int d = 0; d < D_; ++d) {
                double ev = (double)E[(size_t)d * K_ + c];
                e2  = fma(ev, ev, e2);
                dot = fma((double)zr[d], ev, dot);
            }
            double dist = e2 - 2.0 * dot;
            if (dist < bd || (dist == bd && c < bi)) { bd = dist; bi = c; }
        }
        sd[threadIdx.x] = bd; si[threadIdx.x] = bi;
        __syncthreads();
        for (int s = 128; s > 0; s >>= 1) {
            if (threadIdx.x < s) {
                double od = sd[threadIdx.x + s]; int oi = si[threadIdx.x + s];
                if (od < sd[threadIdx.x] || (od == sd[threadIdx.x] && oi < si[threadIdx.x])) {
                    sd[threadIdx.x] = od; si[threadIdx.x] = oi;
                }
            }
            __syncthreads();
        }
        if (threadIdx.x == 0) code[row] = si[0];
    }
}

// ---------------- histogram of codes (LDS-staged) ----------------
__global__ void k_hist(const int* __restrict__ code, int* __restrict__ counts) {
    __shared__ int h[K_];
    int t = threadIdx.x;
    #pragma unroll
    for (int j = t; j < K_; j += 256) h[j] = 0;
    __syncthreads();
    int r = blockIdx.x * 256 + t;
    atomicAdd(&h[code[r]], 1);
    __syncthreads();
    #pragma unroll
    for (int j = t; j < K_; j += 256) {
        int v = h[j];
        if (v) atomicAdd(&counts[j], v);
    }
}

// ---------------- exclusive prefix scan over 1024 counts ----------------
__global__ void k_prefix(const int* __restrict__ counts, int* __restrict__ offsets,
                         int* __restrict__ cursor) {
    __shared__ int s[K_];
    int t = threadIdx.x;
    int v = counts[t];
    s[t] = v;
    __syncthreads();
    for (int d = 1; d < K_; d <<= 1) {
        int x = (t >= d) ? s[t - d] : 0;
        __syncthreads();
        s[t] += x;
        __syncthreads();
    }
    int excl = s[t] - v;
    offsets[t] = excl;
    cursor[t]  = excl;
    if (t == K_ - 1) offsets[K_] = s[t];
}

// ---------------- counting-sort: row indices into cluster order ----------------
__global__ void k_sortidx(const int* __restrict__ code, int* __restrict__ cursor,
                          int* __restrict__ sorted) {
    int r = blockIdx.x * 256 + threadIdx.x;
    int c = code[r];
    int pos = atomicAdd(&cursor[c], 1);
    sorted[pos] = r;
}

// ---------------- segment sum: one block per cluster, coalesced gather ----------------
__global__ void k_segsum(const float* __restrict__ z, const int* __restrict__ sorted,
                         const int* __restrict__ offsets, float* __restrict__ emb_sum) {
    int k = blockIdx.x, d = threadIdx.x;
    int beg = offsets[k], end = offsets[k + 1];
    float s = 0.f;
    int j = beg;
    for (; j + 4 <= end; j += 4) {
        int r0 = sorted[j], r1 = sorted[j + 1], r2 = sorted[j + 2], r3 = sorted[j + 3];
        float v0 = z[(size_t)r0 * D_ + d];
        float v1 = z[(size_t)r1 * D_ + d];
        float v2 = z[(size_t)r2 * D_ + d];
        float v3 = z[(size_t)r3 * D_ + d];
        s += (v0 + v1) + (v2 + v3);
    }
    for (; j < end; ++j) s += z[(size_t)sorted[j] * D_ + d];
    emb_sum[(size_t)k * D_ + d] = s;
}

// ---------------- cluster-size EMA + Laplace norm ----------------
__global__ void k_cs(const float* __restrict__ cs, const int* __restrict__ counts,
                     float* __restrict__ out_newcs, float* __restrict__ csnorm) {
    __shared__ float red[K_];
    int k = threadIdx.x;
    float ncs = cs[k] * DECAYF + OMDECAYF * (float)counts[k];
    out_newcs[k] = ncs;
    red[k] = ncs;
    __syncthreads();
    for (int s = 512; s > 0; s >>= 1) {
        if (k < s) red[k] += red[k + s];
        __syncthreads();
    }
    float n = red[0];
    csnorm[k] = (ncs + EPSF) / (n + (float)K_ * EPSF) * n;
}

// ---------------- embedding-mean EMA + normalized codebook ----------------
__global__ void k_emb(const float* __restrict__ EM, const float* __restrict__ emb_sum,
                      const float* __restrict__ csnorm,
                      float* __restrict__ out_newemb, float* __restrict__ out_newem,
                      float* __restrict__ newembT) {
    int tid = blockIdx.x * 256 + threadIdx.x;
    int k = tid >> 8, d = tid & 255;
    float em  = EM[(size_t)d * K_ + k];
    float nem = em * DECAYF + OMDECAYF * emb_sum[tid];
    float nq  = nem / csnorm[k];
    out_newem [(size_t)d * K_ + k] = nem;
    out_newemb[(size_t)d * K_ + k] = nq;
    newembT[tid] = nq;
}

// ---------------- gather z_q + code + per-block loss partials ----------------
__global__ void k_gather(const float* __restrict__ z, const int* __restrict__ code,
                         const float* __restrict__ newembT,
                         float* __restrict__ out_zq, float* __restrict__ out_code,
                         double* __restrict__ partial) {
    __shared__ double wsum[4];
    int w = threadIdx.x >> 6, l = threadIdx.x & 63;
    int row = blockIdx.x * 4 + w;
    int idx = code[row];
    float4 zv = *(const float4*)(z + (size_t)row * D_ + l * 4);
    float4 ev = *(const float4*)(newembT + (size_t)idx * D_ + l * 4);
    *(float4*)(out_zq + (size_t)row * D_ + l * 4) = ev;
    if (l == 0) out_code[row] = (float)idx;
    float dx = ev.x - zv.x, dy = ev.y - zv.y, dz = ev.z - zv.z, dw = ev.w - zv.w;
    double s = (double)dx * dx + (double)dy * dy + (double)dz * dz + (double)dw * dw;
    for (int off = 32; off > 0; off >>= 1) s += __shfl_down(s, off);
    if (l == 0) wsum[w] = s;
    __syncthreads();
    if (threadIdx.x == 0) partial[blockIdx.x] = wsum[0] + wsum[1] + wsum[2] + wsum[3];
}

// ---------------- finalize losses ----------------
__global__ void k_final(const double* __restrict__ partial, float* __restrict__ out_closs,
                        float* __restrict__ out_cbloss) {
    __shared__ double red[256];
    int b = blockIdx.x;
    double s = 0.0;
    for (int j = threadIdx.x; j < 1024; j += 256) s += partial[b * 1024 + j];
    red[threadIdx.x] = s;
    __syncthreads();
    for (int st = 128; st > 0; st >>= 1) {
        if (threadIdx.x < st) red[threadIdx.x] += red[threadIdx.x + st];
        __syncthreads();
    }
    if (threadIdx.x == 0) {
        out_closs[b]  = (float)(red[0] / (double)((size_t)T_ * D_));
        out_cbloss[b] = 0.0f;
    }
}

extern "C" void kernel_launch(void* const* d_in, const int* in_sizes, int n_in,
                              void* d_out, int out_size, void* d_ws, size_t ws_size,
                              hipStream_t stream) {
    (void)in_sizes; (void)n_in; (void)out_size; (void)ws_size;
    const float* z  = (const float*)d_in[0];
    const float* E  = (const float*)d_in[1];
    const float* cs = (const float*)d_in[2];
    const float* EM = (const float*)d_in[3];

    float* out       = (float*)d_out;
    float* out_zq    = out;                         // 16777216 floats
    float* out_closs = out + 16777216;              // 16
    float* out_cbl   = out_closs + 16;              // 16
    float* out_code  = out_cbl + 16;                // 65536
    float* out_nemb  = out_code + 65536;            // 262144
    float* out_ncs   = out_nemb + 262144;           // 1024
    float* out_nem   = out_ncs + 1024;              // 262144

    // z_hi / z_lo live in the z_q output region (fully overwritten by k_gather)
    u16* zh = (u16*)out_zq;                 // 32MB
    u16* zl = (u16*)(out_zq + 8388608);     // 32MB

    char* w = (char*)d_ws;
    int*    counts  = (int*)(w + 0);                // 4096 B  (zeroed)
    int*    nflag   = (int*)(w + 4096);             // 64 B    (zeroed)
    int*    offsets = (int*)(w + 4160);             // 4104 B (1025 ints)
    int*    cursor  = (int*)(w + 8320);             // 4096 B
    double* partial = (double*)(w + 12416);         // 131072 B
    float*  emb_sum = (float*)(w + 143488);         // 1048576 B
    float*  enorm   = (float*)(w + 1192064);        // 4096 B
    int*    code_i  = (int*)(w + 1196160);          // 262144 B
    int*    flags   = (int*)(w + 1458304);          // 262144 B
    float*  csnorm  = (float*)(w + 1720448);        // 4096 B
    float*  newembT = (float*)(w + 1724544);        // 1048576 B
    u16*    EhT     = (u16*)(w + 2773120);          // 524288 B
    u16*    ElT     = (u16*)(w + 3297408);          // 524288 B
    int*    sorted  = (int*)(w + 3821696);          // 262144 B  (end ~4.08 MB)

    // zero counts + nflag only
    k_zero<<<(1040 + 255) / 256, 256, 0, stream>>>((uint32_t*)d_ws, 1040);

    k_split_z<<<BT_ * D_ / (256 * 8), 256, 0, stream>>>(z, zh, zl);
    k_prepE  <<<K_, 256, 0, stream>>>(E, EhT, ElT, enorm);
    k_argmin_mfma<<<BT_ / 128, 512, 0, stream>>>(zh, zl, EhT, ElT, enorm,
                                                 code_i, flags, nflag);
    k_fixup  <<<256, 256, 0, stream>>>(z, E, nflag, flags, code_i);

    // counting-sort based segment sum (replaces atomic scatter)
    k_hist   <<<BT_ / 256, 256, 0, stream>>>(code_i, counts);
    k_prefix <<<1, K_, 0, stream>>>(counts, offsets, cursor);
    k_sortidx<<<BT_ / 256, 256, 0, stream>>>(code_i, cursor, sorted);
    k_segsum <<<K_, 256, 0, stream>>>(z, sorted, offsets, emb_sum);

    k_cs     <<<1, K_, 0, stream>>>(cs, counts, out_ncs, csnorm);
    k_emb    <<<(K_ * D_) / 256, 256, 0, stream>>>(EM, emb_sum, csnorm,
                                                   out_nemb, out_nem, newembT);
    k_gather <<<BT_ / 4, 256, 0, stream>>>(z, code_i, newembT, out_zq, out_code, partial);
    k_final  <<<B_, 256, 0, stream>>>(partial, out_closs, out_cbl);
}